// Round 7
// baseline (330.915 us; speedup 1.0000x reference)
//
#include <hip/hip_runtime.h>
#include <stdint.h>

#define NH 16
#define DH 64
#define DM 1024
#define Bz 4
#define Sz 2048
#define NKT 16   // K tiles of 64 in DM

typedef __bf16 bf16x8 __attribute__((ext_vector_type(8)));
typedef float f32x4 __attribute__((ext_vector_type(4)));

// async global(16B/lane) -> LDS (wave-uniform base + lane*16)
#define GLD_LDS16(gsrc, ldst)                                             \
    __builtin_amdgcn_global_load_lds(                                     \
        (const __attribute__((address_space(1))) void*)(gsrc),            \
        (__attribute__((address_space(3))) void*)(ldst), 16, 0, 0)

__device__ __forceinline__ unsigned short f2bf(float f) {
    unsigned u = __float_as_uint(f);
    u += 0x7FFFu + ((u >> 16) & 1u);          // RNE
    return (unsigned short)(u >> 16);
}
__device__ __forceinline__ float bf2f(unsigned short h) {
    return __uint_as_float(((unsigned)h) << 16);
}

// ---------------------------------------------------------------------------
// Dtype detection (f32 vs bf16 storage). flag=1 => f32.
// ---------------------------------------------------------------------------
__global__ void detect_dtype(const unsigned short* __restrict__ xs,
                             int* __restrict__ flagp)
{
    const int t = threadIdx.x;          // 64 threads, 1 block
    int cnt = 0;
    for (int i = 0; i < 64; i++) {
        const unsigned short h = xs[(t * 64 + i) * 2];
        const int e = (h >> 7) & 0xFF;
        if (h != 0 && e >= 100 && e <= 130) cnt++;
    }
#pragma unroll
    for (int off = 32; off >= 1; off >>= 1)
        cnt += __shfl_xor(cnt, off);
    if (t == 0) *flagp = (cnt < 2048) ? 1 : 0;
}

// ---------------------------------------------------------------------------
// Canonicalize 9 tensors into bf16 workspace buffers.
// ---------------------------------------------------------------------------
__global__ __launch_bounds__(256) void convert_inputs(
    const void* s0, const void* s1, const void* s2, const void* s3,
    const void* s4, const void* s5, const void* s6, const void* s7,
    const void* s8,
    unsigned short* d0, unsigned short* d1, unsigned short* d2,
    unsigned short* d3, unsigned short* d4, unsigned short* d5,
    unsigned short* d6, unsigned short* d7, unsigned short* d8,
    const int* __restrict__ flagp)
{
    const void* s; unsigned short* d; int n;
    switch (blockIdx.y) {
        case 0: s = s0; d = d0; n = Bz * Sz * DM; break;   // x
        case 1: s = s1; d = d1; n = DM * DM; break;        // Wq
        case 2: s = s2; d = d2; n = DM * DM; break;        // Wk
        case 3: s = s3; d = d3; n = DM * DM; break;        // Wv
        case 4: s = s4; d = d4; n = DM * DM; break;        // Wo
        case 5: s = s5; d = d5; n = DM; break;             // bq
        case 6: s = s6; d = d6; n = DM; break;             // bk
        case 7: s = s7; d = d7; n = DM; break;             // bv
        default: s = s8; d = d8; n = DM; break;            // bo
    }
    const int flag   = *flagp;
    const int stride = gridDim.x * blockDim.x * 4;
    const int base   = (blockIdx.x * blockDim.x + threadIdx.x) * 4;
    if (flag) {
        const float* sf = (const float*)s;
        for (int i = base; i < n; i += stride) {
            const float4 v = *reinterpret_cast<const float4*>(&sf[i]);
            ushort2 a, b;
            a.x = f2bf(v.x); a.y = f2bf(v.y);
            b.x = f2bf(v.z); b.y = f2bf(v.w);
            *reinterpret_cast<ushort2*>(&d[i])     = a;
            *reinterpret_cast<ushort2*>(&d[i + 2]) = b;
        }
    } else {
        const unsigned short* sh = (const unsigned short*)s;
        for (int i = base; i < n; i += stride)
            *reinterpret_cast<uint2*>(&d[i]) = *reinterpret_cast<const uint2*>(&sh[i]);
    }
}

// ===========================================================================
// R11: 256x256 8-wave GEMM with COUNTED-vmcnt half-split schedule (T3+T4).
// R6 closed swizzle/FETCH/occupancy hypotheses (all moved, dur didn't).
// Last untested schedule lever = drain-0 vs counted (m218: +38-73%).
// Per K-tile (4 phases):
//   ph1: issue stageH0(t+1) | read A0-3,B0-1(cur) | 16 MFMA Q00
//        vmcnt(4) [H1(t) landed, H0(t+1) flies] + barrier
//   ph2: issue stageH1(t+1) | read B2-3(cur) | 16 MFMA Q01
//   ph3: read A4-7(cur) | 16 MFMA Q11 | 16 MFMA Q10
//        vmcnt(4) [H0(t+1) landed, H1(t+1) flies] + barrier
// Halves aligned with consumption: H0 = {A rows ==[0,64) mod 128;
// B rows ==[0,32) mod 64} = exactly ph1's fragment rows; H1 = rest.
// WAR: nxt-buffer writes touch data fully consumed before prev closing
// barrier. Invariant entering tile t: outstanding = H1(t) <= 4.
// Swizzle (T2/T21) and XCD remap (T1) carried from R6 (conflicts = 0).
// ===========================================================================

// swizzled LDS read of one bf16x8 fragment; R = local row, c = col byte
__device__ __forceinline__ bf16x8 lds_frag(const unsigned short* lds, int R, int c) {
    const int cs = c ^ ((R & 7) << 4);
    return *reinterpret_cast<const bf16x8*>(
        reinterpret_cast<const char*>(lds) + R * 128 + cs);
}

// ---------------------------------------------------------------------------
// QKV projection. R11 layout change: Q,K stored as [b*s][e] row-major
// (GEMM-natural C rows -> dense epilogue writes); Vt stays [bh][d][s].
// grid: 384 blocks x 512 threads; XCD remap proj-outer.
// ---------------------------------------------------------------------------
__global__ __launch_bounds__(512, 2) void gemm_qkv(
    const unsigned short* __restrict__ X,
    const unsigned short* __restrict__ Wq,
    const unsigned short* __restrict__ Wk,
    const unsigned short* __restrict__ Wv,
    const unsigned short* __restrict__ bq,
    const unsigned short* __restrict__ bk,
    const unsigned short* __restrict__ bv,
    unsigned short* __restrict__ Qb,      // [8192][1024]
    unsigned short* __restrict__ Kb,      // [8192][1024]
    unsigned short* __restrict__ Vtb)     // [64][64][2048]
{
    __shared__ __align__(16) unsigned short Alds[2][256 * 64];   // 64 KB
    __shared__ __align__(16) unsigned short Blds[2][256 * 64];   // 64 KB

    const int tid  = threadIdx.x;
    const int w    = tid >> 6, lane = tid & 63;
    const int quad = lane >> 4, l15 = lane & 15;
    const int wr   = w >> 2, wc = w & 3;          // 2M x 4N wave grid

    // XCD remap: flat -> (proj, bm, bn). 384 = 8 XCD x (3 proj x 16)
    const int flat = (int)blockIdx.x;             // 0..383
    const int k8   = flat & 7;
    const int m    = flat >> 3;                   // 0..47
    const int proj = m >> 4;                      // 0..2
    const int mm   = m & 15;                      // 0..15
    const int bm   = (k8 * 4 + (mm >> 2)) * 256;  // 0..7936
    const int bn   = (mm & 3) * 256;              // 0..768

    const unsigned short* W      = proj == 0 ? Wq : (proj == 1 ? Wk : Wv);
    const unsigned short* bias_p = proj == 0 ? bq : (proj == 1 ? bk : bv);
    const unsigned short* Abase  = X + (size_t)bm * DM;
    const unsigned short* Bbase  = W + (size_t)bn * DM;

    // staging geometry
    const int srow = 8 * w + (lane >> 3);                     // 0..63
    const int scb  = (lane & 7) * 16;                         // col byte 0..112
    const int sse  = (scb ^ ((srow & 7) << 4)) >> 1;          // pre-swizzled col elem
    const int br0  = (srow & 31) + ((srow >> 5) << 6);        // B H0 rows: [0,32)u[64,96)
    const int bB   = 8 * w + ((w >= 4) ? 32 : 0);             // wave-uniform B lds base row

    f32x4 acc[8][4];
#pragma unroll
    for (int i = 0; i < 8; i++)
#pragma unroll
        for (int j = 0; j < 4; j++)
            acc[i][j] = f32x4{0.f, 0.f, 0.f, 0.f};

    // H0: A rows ==[0,64) mod 128; B rows ==[0,32) mod 64   (4 loads/thread)
    auto stageH0 = [&](int buf, int kt) {
        const int kc = kt * 64;
        GLD_LDS16(&Abase[(size_t)(srow      ) * DM + kc + sse], &Alds[buf][(8 * w      ) * 64]);
        GLD_LDS16(&Abase[(size_t)(srow + 128) * DM + kc + sse], &Alds[buf][(8 * w + 128) * 64]);
        GLD_LDS16(&Bbase[(size_t)(br0       ) * DM + kc + sse], &Blds[buf][(bB         ) * 64]);
        GLD_LDS16(&Bbase[(size_t)(br0  + 128) * DM + kc + sse], &Blds[buf][(bB    + 128) * 64]);
    };
    // H1: the complementary halves
    auto stageH1 = [&](int buf, int kt) {
        const int kc = kt * 64;
        GLD_LDS16(&Abase[(size_t)(srow +  64) * DM + kc + sse], &Alds[buf][(8 * w +  64) * 64]);
        GLD_LDS16(&Abase[(size_t)(srow + 192) * DM + kc + sse], &Alds[buf][(8 * w + 192) * 64]);
        GLD_LDS16(&Bbase[(size_t)(br0  +  32) * DM + kc + sse], &Blds[buf][(bB    +  32) * 64]);
        GLD_LDS16(&Bbase[(size_t)(br0  + 160) * DM + kc + sse], &Blds[buf][(bB    + 160) * 64]);
    };

    // prologue: tile 0 both halves; wait H0 only (H1 may stay in flight)
    stageH0(0, 0);
    stageH1(0, 0);
    asm volatile("s_waitcnt vmcnt(4)" ::: "memory");
    __builtin_amdgcn_s_barrier();
    asm volatile("" ::: "memory");

    for (int T = 0; T < NKT; ++T) {
        const int cur = T & 1, nxt = cur ^ 1;
        const unsigned short* A = &Alds[cur][0];
        const unsigned short* B = &Blds[cur][0];
        const int aR0 = wr * 128 + l15;
        const int bR0 = wc * 64 + l15;

        bf16x8 aR[4][2], b01[2][2], b23[2][2];

        // ---- ph1: stage H0(T+1); read A0-3 + B0-1; MFMA Q00 ----
        if (T < NKT - 1) stageH0(nxt, T + 1);
#pragma unroll
        for (int mi = 0; mi < 4; mi++) {
            aR[mi][0] = lds_frag(A, aR0 + mi * 16, quad * 16);
            aR[mi][1] = lds_frag(A, aR0 + mi * 16, quad * 16 + 64);
        }
#pragma unroll
        for (int nj = 0; nj < 2; nj++) {
            b01[nj][0] = lds_frag(B, bR0 + nj * 16, quad * 16);
            b01[nj][1] = lds_frag(B, bR0 + nj * 16, quad * 16 + 64);
        }
        __builtin_amdgcn_s_setprio(1);
#pragma unroll
        for (int mi = 0; mi < 4; mi++)
#pragma unroll
            for (int nj = 0; nj < 2; nj++) {
                acc[mi][nj] = __builtin_amdgcn_mfma_f32_16x16x32_bf16(aR[mi][0], b01[nj][0], acc[mi][nj], 0, 0, 0);
                acc[mi][nj] = __builtin_amdgcn_mfma_f32_16x16x32_bf16(aR[mi][1], b01[nj][1], acc[mi][nj], 0, 0, 0);
            }
        __builtin_amdgcn_s_setprio(0);
        if (T < NKT - 1) { asm volatile("s_waitcnt vmcnt(4)" ::: "memory"); }
        else             { asm volatile("s_waitcnt vmcnt(0)" ::: "memory"); }
        __builtin_amdgcn_s_barrier();
        asm volatile("" ::: "memory");

        // ---- ph2: stage H1(T+1); read B2-3; MFMA Q01 ----
        if (T < NKT - 1) stageH1(nxt, T + 1);
#pragma unroll
        for (int nj = 0; nj < 2; nj++) {
            b23[nj][0] = lds_frag(B, bR0 + (nj + 2) * 16, quad * 16);
            b23[nj][1] = lds_frag(B, bR0 + (nj + 2) * 16, quad * 16 + 64);
        }
        __builtin_amdgcn_s_setprio(1);
#pragma unroll
        for (int mi = 0; mi < 4; mi++)
#pragma unroll
            for (int nj = 0; nj < 2; nj++) {
                acc[mi][nj + 2] = __builtin_amdgcn_mfma_f32_16x16x32_bf16(aR[mi][0], b23[nj][0], acc[mi][nj + 2], 0, 0, 0);
                acc[mi][nj + 2] = __builtin_amdgcn_mfma_f32_16x16x32_bf16(aR[mi][1], b23[nj][1], acc[mi][nj + 2], 0, 0, 0);
            }
        __builtin_amdgcn_s_setprio(0);

        // ---- ph3: read A4-7; MFMA Q11 + Q10 ----
#pragma unroll
        for (int mi = 0; mi < 4; mi++) {
            aR[mi][0] = lds_frag(A, aR0 + (mi + 4) * 16, quad * 16);
            aR[mi][1] = lds_frag(A, aR0 + (mi + 4) * 16, quad * 16 + 64);
        }
        __builtin_amdgcn_s_setprio(1);
#pragma unroll
        for (int mi = 0; mi < 4; mi++)
#pragma unroll
            for (int nj = 0; nj < 2; nj++) {
                acc[mi + 4][nj + 2] = __builtin_amdgcn_mfma_f32_16x16x32_bf16(aR[mi][0], b23[nj][0], acc[mi + 4][nj + 2], 0, 0, 0);
                acc[mi + 4][nj + 2] = __builtin_amdgcn_mfma_f32_16x16x32_bf16(aR[mi][1], b23[nj][1], acc[mi + 4][nj + 2], 0, 0, 0);
            }
#pragma unroll
        for (int mi = 0; mi < 4; mi++)
#pragma unroll
            for (int nj = 0; nj < 2; nj++) {
                acc[mi + 4][nj] = __builtin_amdgcn_mfma_f32_16x16x32_bf16(aR[mi][0], b01[nj][0], acc[mi + 4][nj], 0, 0, 0);
                acc[mi + 4][nj] = __builtin_amdgcn_mfma_f32_16x16x32_bf16(aR[mi][1], b01[nj][1], acc[mi + 4][nj], 0, 0, 0);
            }
        __builtin_amdgcn_s_setprio(0);

        if (T < NKT - 1) { asm volatile("s_waitcnt vmcnt(4)" ::: "memory"); }
        else             { asm volatile("s_waitcnt vmcnt(0)" ::: "memory"); }
        __builtin_amdgcn_s_barrier();
        asm volatile("" ::: "memory");
    }

    // epilogue
    if (proj < 2) {
        // Q,K: [b*s][e] row-major -> dense row writes
        unsigned short* dst = (proj == 0) ? Qb : Kb;
#pragma unroll
        for (int nj = 0; nj < 4; nj++) {
            const int   e    = bn + wc * 64 + nj * 16 + l15;
            const float bias = bf2f(bias_p[e]);
#pragma unroll
            for (int mi = 0; mi < 8; mi++) {
#pragma unroll
                for (int r = 0; r < 4; r++) {
                    const int mrow = bm + wr * 128 + mi * 16 + quad * 4 + r;
                    dst[(size_t)mrow * DM + e] = f2bf(acc[mi][nj][r] + bias);
                }
            }
        }
    } else {
        // V transposed: 4 consecutive s per lane -> one uint2 store
#pragma unroll
        for (int nj = 0; nj < 4; nj++) {
            const int   e    = bn + wc * 64 + nj * 16 + l15;
            const int   h    = e >> 6, dd = e & 63;
            const float bias = bf2f(bias_p[e]);
#pragma unroll
            for (int mi = 0; mi < 8; mi++) {
                const int m0 = bm + wr * 128 + mi * 16 + quad * 4;   // s-aligned to 4
                const int b  = m0 >> 11, s0 = m0 & 2047;
                const unsigned u0 = __float_as_uint(acc[mi][nj][0] + bias) + 0x8000u;
                const unsigned u1 = __float_as_uint(acc[mi][nj][1] + bias) + 0x8000u;
                const unsigned u2 = __float_as_uint(acc[mi][nj][2] + bias) + 0x8000u;
                const unsigned u3 = __float_as_uint(acc[mi][nj][3] + bias) + 0x8000u;
                uint2 pk;
                pk.x = __builtin_amdgcn_perm(u1, u0, 0x07060302u);
                pk.y = __builtin_amdgcn_perm(u3, u2, 0x07060302u);
                *reinterpret_cast<uint2*>(
                    &Vtb[((size_t)(b * NH + h) * DH + dd) * Sz + s0]) = pk;
            }
        }
    }
}

// ---------------------------------------------------------------------------
// Flash attention — R5-passing structure; ONLY the Q/K base addressing
// changed for the new [b*s][e] layout (3 load sites). Vt unchanged.
// ---------------------------------------------------------------------------
__global__ __launch_bounds__(512) void flash_attn(
    const unsigned short* __restrict__ Qb,    // [8192][1024]
    const unsigned short* __restrict__ Kb,    // [8192][1024]
    const unsigned short* __restrict__ Vtb,   // [64][64][2048]
    unsigned short* __restrict__ AOb)         // [4][2048][1024]
{
    __shared__ __align__(16) unsigned short Ks[64 * 72];    // [kv][d]
    __shared__ __align__(16) unsigned short Vs[64 * 72];    // [d][kv]
    __shared__ __align__(16) unsigned short Ps[128 * 72];   // [q][kv], wave-private rows

    const int tid  = threadIdx.x;
    const int w    = tid >> 6, lane = tid & 63;
    const int quad = lane >> 4, l15 = lane & 15;

    // XCD-locality remap: flat -> (bh, cA); bh % 8 == XCD id
    const int flat = (int)(blockIdx.y * gridDim.x + blockIdx.x);  // 0..511
    const int k8   = flat & 7;
    const int m    = flat >> 3;          // 0..63
    const int bh   = k8 + 8 * (m >> 3);  // 8 heads per XCD
    const int cA   = m & 7;

    const int srow = tid >> 3;            // 0..63  (512 threads)
    const int scc  = (tid & 7) * 8;       // 0..56
    const int hh = bh & 15, bb = bh >> 4;

    for (int pass = 0; pass < 2; pass++) {
        const int chunk = pass ? (15 - cA) : cA;
        const int qb = chunk * 128;
        const int qw = qb + w * 16;                  // wave's 16 q rows

        // Q fragment from [b*s][e]: row = bb*Sz + q, col = hh*64 + d
        const size_t qbase = ((size_t)(bb * Sz + qw + l15)) * DM + hh * DH;
        const bf16x8 qf0 = *reinterpret_cast<const bf16x8*>(&Qb[qbase + quad * 8]);
        const bf16x8 qf1 = *reinterpret_cast<const bf16x8*>(&Qb[qbase + 32 + quad * 8]);

        f32x4 o[4];
#pragma unroll
        for (int jd = 0; jd < 4; jd++) o[jd] = f32x4{0.f, 0.f, 0.f, 0.f};
        float lsum = 0.f;

        const int n_kv = qb + 128;                   // multiple of 128

        auto compute = [&](int kb) {
            const bool need_mask = (kb + 64 > qw);
#pragma unroll
            for (int j = 0; j < 4; j++) {
                const bf16x8 kf0 = *reinterpret_cast<const bf16x8*>(&Ks[(j * 16 + l15) * 72 + quad * 8]);
                const bf16x8 kf1 = *reinterpret_cast<const bf16x8*>(&Ks[(j * 16 + l15) * 72 + 32 + quad * 8]);
                f32x4 st = f32x4{0.f, 0.f, 0.f, 0.f};
                st = __builtin_amdgcn_mfma_f32_16x16x32_bf16(kf0, qf0, st, 0, 0, 0);
                st = __builtin_amdgcn_mfma_f32_16x16x32_bf16(kf1, qf1, st, 0, 0, 0);
                // p = exp(S/8) = exp2(S * 0.125*log2(e)); causal mask via select
                const int qa = qw + l15;
                float p[4];
#pragma unroll
                for (int r = 0; r < 4; r++) {
                    float e = __builtin_amdgcn_exp2f(st[r] * 0.18033688011f);
                    if (need_mask) {
                        const int kv = kb + j * 16 + quad * 4 + r;
                        e = (kv <= qa) ? e : 0.f;
                    }
                    p[r] = e;
                }
                lsum += (p[0] + p[1]) + (p[2] + p[3]);
                const unsigned u0 = __float_as_uint(p[0]) + 0x8000u;
                const unsigned u1 = __float_as_uint(p[1]) + 0x8000u;
                const unsigned u2 = __float_as_uint(p[2]) + 0x8000u;
                const unsigned u3 = __float_as_uint(p[3]) + 0x8000u;
                const unsigned pk0 = __builtin_amdgcn_perm(u1, u0, 0x07060302u);
                const unsigned pk1 = __builtin_amdgcn_perm(u3, u2, 0x07060302u);
                const int prow = (w * 16 + l15) * 72 + j * 16 + quad * 4;
                *reinterpret_cast<unsigned*>(&Ps[prow])     = pk0;
                *reinterpret_cast<unsigned*>(&Ps[prow + 2]) = pk1;
            }

            // wave-private Ps rows: in-wave drain only, no barrier
            asm volatile("s_waitcnt lgkmcnt(0)" ::: "memory");

            const bf16x8 pf0 = *reinterpret_cast<const bf16x8*>(&Ps[(w * 16 + l15) * 72 + quad * 8]);
            const bf16x8 pf1 = *reinterpret_cast<const bf16x8*>(&Ps[(w * 16 + l15) * 72 + 32 + quad * 8]);
#pragma unroll
            for (int jd = 0; jd < 4; jd++) {
                const bf16x8 vf0 = *reinterpret_cast<const bf16x8*>(&Vs[(jd * 16 + l15) * 72 + quad * 8]);
                const bf16x8 vf1 = *reinterpret_cast<const bf16x8*>(&Vs[(jd * 16 + l15) * 72 + 32 + quad * 8]);
                o[jd] = __builtin_amdgcn_mfma_f32_16x16x32_bf16(pf0, vf0, o[jd], 0, 0, 0);
                o[jd] = __builtin_amdgcn_mfma_f32_16x16x32_bf16(pf1, vf1, o[jd], 0, 0, 0);
            }
        };

        // prologue: prefetch tile 0 into registers (K from [b*s][e] layout)
        uint4 kr0 = *reinterpret_cast<const uint4*>(&Kb[((size_t)(bb * Sz + srow)) * DM + hh * DH + scc]);
        uint4 vr0 = *reinterpret_cast<const uint4*>(&Vtb[((size_t)bh * DH + srow) * Sz + scc]);
        uint4 kr1, vr1;

        for (int kb = 0; kb < n_kv; kb += 128) {
            // ---------------- tile kb (regs kr0/vr0) ----------------
            __syncthreads();    // prev compute done; drains kr0/vr0 (used now)
            *reinterpret_cast<uint4*>(&Ks[srow * 72 + scc]) = kr0;
            *reinterpret_cast<uint4*>(&Vs[srow * 72 + scc]) = vr0;
            // prefetch tile kb+64 (always exists: n_kv is a multiple of 128)
            kr1 = *reinterpret_cast<const uint4*>(&Kb[((size_t)(bb * Sz + kb + 64 + srow)) * DM + hh * DH + scc]);
            vr1 = *reinterpret_cast<const uint4*>(&Vtb[((size_t)bh * DH + srow) * Sz + kb + 64 + scc]);
            asm volatile("s_waitcnt lgkmcnt(0)" ::: "memory");
            __builtin_amdgcn_s_barrier();             // raw: keep prefetch in flight
            asm volatile("" ::: "memory");
            if (kb <= qw + 15) compute(kb);

            // ---------------- tile kb+64 (regs kr1/vr1) ----------------
            __syncthreads();
            *reinterpret_cast<uint4*>(&Ks[srow * 72 + scc]) = kr1;
            *reinterpret_cast<uint4*>(&Vs[srow * 72 + scc]) = vr1;
            if (kb + 128 < n_kv) {
                kr0 = *reinterpret_cast<const uint4*>(&Kb[((size_t)(bb * Sz + kb + 128 + srow)) * DM + hh * DH + scc]);
                vr0 = *reinterpret_cast<const uint4*>(&Vtb[((size_t)bh * DH + srow) * Sz + kb + 128 + scc]);
            }
            asm volatile("s_waitcnt lgkmcnt(0)" ::: "memory");
            __builtin_amdgcn_s_barrier();
            asm volatile("" ::: "memory");
            if (kb + 64 <= qw + 15) compute(kb + 64);
        }

        // reduce lsum across quads (lane holds partial for q = qw + l15)
        lsum += __shfl_xor(lsum, 16);
        lsum += __shfl_xor(lsum, 32);

        // write AO[b][s][h*64+d]; o[jd][r] is q-row quad*4+r, col jd*16+l15
        float linv[4];
#pragma unroll
        for (int r = 0; r < 4; r++)
            linv[r] = 1.0f / __shfl(lsum, quad * 4 + r);
#pragma unroll
        for (int jd = 0; jd < 4; jd++) {
#pragma unroll
            for (int r = 0; r < 4; r++) {
                const int s = qw + quad * 4 + r;
                AOb[((size_t)(bb * Sz + s)) * DM + hh * DH + jd * 16 + l15] =
                    f2bf(o[jd][r] * linv[r]);
            }
        }
    }
}

// ---------------------------------------------------------------------------
// Output projection: same R11 counted-vmcnt template. grid: 128 x 512.
// ---------------------------------------------------------------------------
__global__ __launch_bounds__(512, 2) void gemm_out(
    const unsigned short* __restrict__ Ain,
    const unsigned short* __restrict__ W,
    const unsigned short* __restrict__ bo,
    void* __restrict__ outv,
    const int* __restrict__ flagp)
{
    __shared__ __align__(16) unsigned short Alds[2][256 * 64];
    __shared__ __align__(16) unsigned short Blds[2][256 * 64];

    const int tid  = threadIdx.x;
    const int w    = tid >> 6, lane = tid & 63;
    const int quad = lane >> 4, l15 = lane & 15;
    const int wr   = w >> 2, wc = w & 3;

    const int flat = (int)blockIdx.x;             // 0..127
    const int k8   = flat & 7;
    const int m    = flat >> 3;                   // 0..15
    const int bm   = (k8 * 4 + (m >> 2)) * 256;
    const int bn   = (m & 3) * 256;

    const unsigned short* Abase = Ain + (size_t)bm * DM;
    const unsigned short* Bbase = W   + (size_t)bn * DM;

    const int srow = 8 * w + (lane >> 3);
    const int scb  = (lane & 7) * 16;
    const int sse  = (scb ^ ((srow & 7) << 4)) >> 1;
    const int br0  = (srow & 31) + ((srow >> 5) << 6);
    const int bB   = 8 * w + ((w >= 4) ? 32 : 0);

    f32x4 acc[8][4];
#pragma unroll
    for (int i = 0; i < 8; i++)
#pragma unroll
        for (int j = 0; j < 4; j++)
            acc[i][j] = f32x4{0.f, 0.f, 0.f, 0.f};

    auto stageH0 = [&](int buf, int kt) {
        const int kc = kt * 64;
        GLD_LDS16(&Abase[(size_t)(srow      ) * DM + kc + sse], &Alds[buf][(8 * w      ) * 64]);
        GLD_LDS16(&Abase[(size_t)(srow + 128) * DM + kc + sse], &Alds[buf][(8 * w + 128) * 64]);
        GLD_LDS16(&Bbase[(size_t)(br0       ) * DM + kc + sse], &Blds[buf][(bB         ) * 64]);
        GLD_LDS16(&Bbase[(size_t)(br0  + 128) * DM + kc + sse], &Blds[buf][(bB    + 128) * 64]);
    };
    auto stageH1 = [&](int buf, int kt) {
        const int kc = kt * 64;
        GLD_LDS16(&Abase[(size_t)(srow +  64) * DM + kc + sse], &Alds[buf][(8 * w +  64) * 64]);
        GLD_LDS16(&Abase[(size_t)(srow + 192) * DM + kc + sse], &Alds[buf][(8 * w + 192) * 64]);
        GLD_LDS16(&Bbase[(size_t)(br0  +  32) * DM + kc + sse], &Blds[buf][(bB    +  32) * 64]);
        GLD_LDS16(&Bbase[(size_t)(br0  + 160) * DM + kc + sse], &Blds[buf][(bB    + 160) * 64]);
    };

    stageH0(0, 0);
    stageH1(0, 0);
    asm volatile("s_waitcnt vmcnt(4)" ::: "memory");
    __builtin_amdgcn_s_barrier();
    asm volatile("" ::: "memory");

    for (int T = 0; T < NKT; ++T) {
        const int cur = T & 1, nxt = cur ^ 1;
        const unsigned short* A = &Alds[cur][0];
        const unsigned short* B = &Blds[cur][0];
        const int aR0 = wr * 128 + l15;
        const int bR0 = wc * 64 + l15;

        bf16x8 aR[4][2], b01[2][2], b23[2][2];

        if (T < NKT - 1) stageH0(nxt, T + 1);
#pragma unroll
        for (int mi = 0; mi < 4; mi++) {
            aR[mi][0] = lds_frag(A, aR0 + mi * 16, quad * 16);
            aR[mi][1] = lds_frag(A, aR0 + mi * 16, quad * 16 + 64);
        }
#pragma unroll
        for (int nj = 0; nj < 2; nj++) {
            b01[nj][0] = lds_frag(B, bR0 + nj * 16, quad * 16);
            b01[nj][1] = lds_frag(B, bR0 + nj * 16, quad * 16 + 64);
        }
        __builtin_amdgcn_s_setprio(1);
#pragma unroll
        for (int mi = 0; mi < 4; mi++)
#pragma unroll
            for (int nj = 0; nj < 2; nj++) {
                acc[mi][nj] = __builtin_amdgcn_mfma_f32_16x16x32_bf16(aR[mi][0], b01[nj][0], acc[mi][nj], 0, 0, 0);
                acc[mi][nj] = __builtin_amdgcn_mfma_f32_16x16x32_bf16(aR[mi][1], b01[nj][1], acc[mi][nj], 0, 0, 0);
            }
        __builtin_amdgcn_s_setprio(0);
        if (T < NKT - 1) { asm volatile("s_waitcnt vmcnt(4)" ::: "memory"); }
        else             { asm volatile("s_waitcnt vmcnt(0)" ::: "memory"); }
        __builtin_amdgcn_s_barrier();
        asm volatile("" ::: "memory");

        if (T < NKT - 1) stageH1(nxt, T + 1);
#pragma unroll
        for (int nj = 0; nj < 2; nj++) {
            b23[nj][0] = lds_frag(B, bR0 + (nj + 2) * 16, quad * 16);
            b23[nj][1] = lds_frag(B, bR0 + (nj + 2) * 16, quad * 16 + 64);
        }
        __builtin_amdgcn_s_setprio(1);
#pragma unroll
        for (int mi = 0; mi < 4; mi++)
#pragma unroll
            for (int nj = 0; nj < 2; nj++) {
                acc[mi][nj + 2] = __builtin_amdgcn_mfma_f32_16x16x32_bf16(aR[mi][0], b23[nj][0], acc[mi][nj + 2], 0, 0, 0);
                acc[mi][nj + 2] = __builtin_amdgcn_mfma_f32_16x16x32_bf16(aR[mi][1], b23[nj][1], acc[mi][nj + 2], 0, 0, 0);
            }
        __builtin_amdgcn_s_setprio(0);

#pragma unroll
        for (int mi = 0; mi < 4; mi++) {
            aR[mi][0] = lds_frag(A, aR0 + (mi + 4) * 16, quad * 16);
            aR[mi][1] = lds_frag(A, aR0 + (mi + 4) * 16, quad * 16 + 64);
        }
        __builtin_amdgcn_s_setprio(1);
#pragma unroll
        for (int mi = 0; mi < 4; mi++)
#pragma unroll
            for (int nj = 0; nj < 2; nj++) {
                acc[mi + 4][nj + 2] = __builtin_amdgcn_mfma_f32_16x16x32_bf16(aR[mi][0], b23[nj][0], acc[mi + 4][nj + 2], 0, 0, 0);
                acc[mi + 4][nj + 2] = __builtin_amdgcn_mfma_f32_16x16x32_bf16(aR[mi][1], b23[nj][1], acc[mi + 4][nj + 2], 0, 0, 0);
            }
#pragma unroll
        for (int mi = 0; mi < 4; mi++)
#pragma unroll
            for (int nj = 0; nj < 2; nj++) {
                acc[mi + 4][nj] = __builtin_amdgcn_mfma_f32_16x16x32_bf16(aR[mi][0], b01[nj][0], acc[mi + 4][nj], 0, 0, 0);
                acc[mi + 4][nj] = __builtin_amdgcn_mfma_f32_16x16x32_bf16(aR[mi][1], b01[nj][1], acc[mi + 4][nj], 0, 0, 0);
            }
        __builtin_amdgcn_s_setprio(0);

        if (T < NKT - 1) { asm volatile("s_waitcnt vmcnt(4)" ::: "memory"); }
        else             { asm volatile("s_waitcnt vmcnt(0)" ::: "memory"); }
        __builtin_amdgcn_s_barrier();
        asm volatile("" ::: "memory");
    }

    const int flag = *flagp;
    float*          outf = (float*)outv;
    unsigned short* outh = (unsigned short*)outv;
#pragma unroll
    for (int nj = 0; nj < 4; nj++) {
        const int   e    = bn + wc * 64 + nj * 16 + l15;
        const float bias = bf2f(bo[e]);
#pragma unroll
        for (int mi = 0; mi < 8; mi++) {
#pragma unroll
            for (int r = 0; r < 4; r++) {
                const int   mrow = bm + wr * 128 + mi * 16 + quad * 4 + r;
                const float v = acc[mi][nj][r] + bias;
                if (flag) outf[(size_t)mrow * DM + e] = v;
                else      outh[(size_t)mrow * DM + e] = f2bf(v);
            }
        }
    }
}

// ---------------------------------------------------------------------------
extern "C" void kernel_launch(void* const* d_in, const int* in_sizes, int n_in,
                              void* d_out, int out_size, void* d_ws, size_t ws_size,
                              hipStream_t stream) {
    // Bind inputs by ELEMENT COUNT (dtype/mask-presence robust)
    const void* x = nullptr;
    const void* Wsrc[4] = {nullptr, nullptr, nullptr, nullptr};
    const void* bsrc[4] = {nullptr, nullptr, nullptr, nullptr};
    int nw = 0, nb = 0;
    for (int i = 0; i < n_in; i++) {
        const int sz = in_sizes[i];
        if (sz == Bz * Sz * DM)            { if (!x) x = d_in[i]; }
        else if (sz == DM * DM)            { if (nw < 4) Wsrc[nw++] = d_in[i]; }
        else if (sz == DM)                 { if (nb < 4) bsrc[nb++] = d_in[i]; }
    }

    char* wsb = (char*)d_ws;
    int*  flagp = (int*)wsb;
    unsigned short* Xc  = (unsigned short*)(wsb + 16);
    const size_t NX = (size_t)Bz * Sz * DM;       // 8,388,608
    const size_t NW = (size_t)DM * DM;            // 1,048,576
    unsigned short* Wc0 = Xc  + NX;
    unsigned short* Wc1 = Wc0 + NW;
    unsigned short* Wc2 = Wc1 + NW;
    unsigned short* Wc3 = Wc2 + NW;
    unsigned short* bc0 = Wc3 + NW;
    unsigned short* bc1 = bc0 + DM;
    unsigned short* bc2 = bc1 + DM;
    unsigned short* bc3 = bc2 + DM;
    unsigned short* Qb  = bc3 + DM;
    const size_t SZ = (size_t)Bz * NH * Sz * DH;  // 8,388,608
    unsigned short* Kb  = Qb  + SZ;
    unsigned short* Vtb = Kb  + SZ;
    unsigned short* AOb = Vtb + SZ;

    detect_dtype<<<1, 64, 0, stream>>>((const unsigned short*)x, flagp);
    convert_inputs<<<dim3(512, 9), 256, 0, stream>>>(
        x, Wsrc[0], Wsrc[1], Wsrc[2], Wsrc[3],
        bsrc[0], bsrc[1], bsrc[2], bsrc[3],
        Xc, Wc0, Wc1, Wc2, Wc3, bc0, bc1, bc2, bc3, flagp);

    gemm_qkv <<<dim3(384), 512, 0, stream>>>(Xc, Wc0, Wc1, Wc2, bc0, bc1, bc2, Qb, Kb, Vtb);
    flash_attn<<<dim3(8, 64), 512, 0, stream>>>(Qb, Kb, Vtb, AOb);
    gemm_out <<<dim3(128), 512, 0, stream>>>(AOb, Wc3, bc3, d_out, flagp);
}

// Round 8
// 288.324 us; speedup vs baseline: 1.1477x; 1.1477x over previous
//
#include <hip/hip_runtime.h>
#include <stdint.h>

#define NH 16
#define DH 64
#define DM 1024
#define Bz 4
#define Sz 2048
#define NKT 16   // K tiles of 64

typedef __bf16 bf16x8 __attribute__((ext_vector_type(8)));
typedef float f32x4 __attribute__((ext_vector_type(4)));
typedef float f32x16 __attribute__((ext_vector_type(16)));

// async global(16B/lane) -> LDS (wave-uniform base + lane*16)
#define GLD_LDS16(gsrc, ldst)                                             \
    __builtin_amdgcn_global_load_lds(                                     \
        (const __attribute__((address_space(1))) void*)(gsrc),            \
        (__attribute__((address_space(3))) void*)(ldst), 16, 0, 0)

__device__ __forceinline__ unsigned short f2bf(float f) {
    unsigned u = __float_as_uint(f);
    u += 0x7FFFu + ((u >> 16) & 1u);          // RNE
    return (unsigned short)(u >> 16);
}
__device__ __forceinline__ float bf2f(unsigned short h) {
    return __uint_as_float(((unsigned)h) << 16);
}

// ---------------------------------------------------------------------------
// Dtype detection (f32 vs bf16 storage). flag=1 => f32.
// ---------------------------------------------------------------------------
__global__ void detect_dtype(const unsigned short* __restrict__ xs,
                             int* __restrict__ flagp)
{
    const int t = threadIdx.x;          // 64 threads, 1 block
    int cnt = 0;
    for (int i = 0; i < 64; i++) {
        const unsigned short h = xs[(t * 64 + i) * 2];
        const int e = (h >> 7) & 0xFF;
        if (h != 0 && e >= 100 && e <= 130) cnt++;
    }
#pragma unroll
    for (int off = 32; off >= 1; off >>= 1)
        cnt += __shfl_xor(cnt, off);
    if (t == 0) *flagp = (cnt < 2048) ? 1 : 0;
}

// ---------------------------------------------------------------------------
// Canonicalize 9 tensors into bf16 workspace buffers.
// ---------------------------------------------------------------------------
__global__ __launch_bounds__(256) void convert_inputs(
    const void* s0, const void* s1, const void* s2, const void* s3,
    const void* s4, const void* s5, const void* s6, const void* s7,
    const void* s8,
    unsigned short* d0, unsigned short* d1, unsigned short* d2,
    unsigned short* d3, unsigned short* d4, unsigned short* d5,
    unsigned short* d6, unsigned short* d7, unsigned short* d8,
    const int* __restrict__ flagp)
{
    const void* s; unsigned short* d; int n;
    switch (blockIdx.y) {
        case 0: s = s0; d = d0; n = Bz * Sz * DM; break;   // x
        case 1: s = s1; d = d1; n = DM * DM; break;        // Wq
        case 2: s = s2; d = d2; n = DM * DM; break;        // Wk
        case 3: s = s3; d = d3; n = DM * DM; break;        // Wv
        case 4: s = s4; d = d4; n = DM * DM; break;        // Wo
        case 5: s = s5; d = d5; n = DM; break;             // bq
        case 6: s = s6; d = d6; n = DM; break;             // bk
        case 7: s = s7; d = d7; n = DM; break;             // bv
        default: s = s8; d = d8; n = DM; break;            // bo
    }
    const int flag   = *flagp;
    const int stride = gridDim.x * blockDim.x * 4;
    const int base   = (blockIdx.x * blockDim.x + threadIdx.x) * 4;
    if (flag) {
        const float* sf = (const float*)s;
        for (int i = base; i < n; i += stride) {
            const float4 v = *reinterpret_cast<const float4*>(&sf[i]);
            ushort2 a, b;
            a.x = f2bf(v.x); a.y = f2bf(v.y);
            b.x = f2bf(v.z); b.y = f2bf(v.w);
            *reinterpret_cast<ushort2*>(&d[i])     = a;
            *reinterpret_cast<ushort2*>(&d[i + 2]) = b;
        }
    } else {
        const unsigned short* sh = (const unsigned short*)s;
        for (int i = base; i < n; i += stride)
            *reinterpret_cast<uint2*>(&d[i]) = *reinterpret_cast<const uint2*>(&sh[i]);
    }
}

// ===========================================================================
// R12: 128x128-tile GEMM with 32x32x16 MFMA (shape experiment).
// Evidence: 5 schedule/swizzle/locality variants all ~100us @ MfmaUtil 21%.
// Shape never varied. 32x32x16 = 2x FLOP per instruction and per operand-VGPR
// read (m119 peak 2495 TF was 32x32; 16x16 ubench = 2075). If an operand-
// delivery/issue hazard is the hidden wall, this is the lever.
// Chassis: BK=64, LDS [128][64] (128B rows), XOR swizzle both-sides (T21):
//   LDS(row, chunk c) holds global(row, c ^ (row&7)); read applies same XOR.
//   Write-side conflict-free; read-side 4-way (32-row fragments, accepted).
// Simple drain schedule (stage next | compute cur | vmcnt0 | barrier) --
// schedules measured irrelevant +-5%. 64KB LDS -> 2 blocks/CU.
// C layout (m74/m101, HW-verified): col = lane&31,
//   row = (reg&3) + 8*(reg>>2) + 4*(lane>>5).
// A/B: row(col) = lane&31, k = (lane>>5)*8 + j  (analog of our verified
//   16x16 pattern row=l15, k=quad*8+j).
// ===========================================================================

// ---------------------------------------------------------------------------
// QKV projection: C = X[8192,1024] @ W[1024,1024]^T + b, scattered to
// Q,K: [b*16+h][s][64]  and  Vt: [b*16+h][d][s]   (all bf16)
// grid: (24,64) = 1536 blocks x 256 threads. R5 XCD remap (proj-outer).
// ---------------------------------------------------------------------------
__global__ __launch_bounds__(256, 2) void gemm_qkv(
    const unsigned short* __restrict__ X,
    const unsigned short* __restrict__ Wq,
    const unsigned short* __restrict__ Wk,
    const unsigned short* __restrict__ Wv,
    const unsigned short* __restrict__ bq,
    const unsigned short* __restrict__ bk,
    const unsigned short* __restrict__ bv,
    unsigned short* __restrict__ Qb,
    unsigned short* __restrict__ Kb,
    unsigned short* __restrict__ Vtb)
{
    __shared__ __align__(16) unsigned short As[2][128 * 64];   // 2 x 16 KB
    __shared__ __align__(16) unsigned short Bs[2][128 * 64];   // 2 x 16 KB

    const int tid  = threadIdx.x;
    const int w    = tid >> 6, lane = tid & 63;
    const int l31  = lane & 31, half = lane >> 5;
    const int wm   = (w & 1) * 64, wn = (w >> 1) * 64;

    // XCD-locality remap (R5): flat -> (proj, bm, bn)
    const int flat = (int)(blockIdx.y * gridDim.x + blockIdx.x);  // 0..1535
    const int k8   = flat & 7;
    const int m    = flat >> 3;         // 0..191
    const int proj = m >> 6;            // 0..2
    const int mm   = m & 63;            // 0..63
    const int bm   = (k8 * 8 + (mm >> 3)) * 128;
    const int bn   = (mm & 7) * 128;

    const unsigned short* W      = proj == 0 ? Wq : (proj == 1 ? Wk : Wv);
    const unsigned short* bias_p = proj == 0 ? bq : (proj == 1 ? bk : bv);
    const unsigned short* Abase  = X + (size_t)bm * DM;
    const unsigned short* Bbase  = W + (size_t)bn * DM;

    // staging: wave covers 8 rows x 128B per instr; t=0..3 -> rows w*32+t*8
    const int sr8 = lane >> 3;                         // 0..7 (row in group)
    const int sce = ((lane & 7) ^ sr8) * 8;            // pre-swizzled col elem

    f32x16 acc[2][2];
#pragma unroll
    for (int i = 0; i < 2; i++)
#pragma unroll
        for (int j = 0; j < 2; j++)
#pragma unroll
            for (int e = 0; e < 16; e++)
                acc[i][j][e] = 0.f;

    auto stage = [&](int buf, int kt) {
        const int kc = kt * 64;
#pragma unroll
        for (int t = 0; t < 4; t++) {
            const int r = w * 32 + t * 8;
            GLD_LDS16(&Abase[(size_t)(r + sr8) * DM + kc + sce], &As[buf][r * 64]);
            GLD_LDS16(&Bbase[(size_t)(r + sr8) * DM + kc + sce], &Bs[buf][r * 64]);
        }
    };

    auto frg = [&](const unsigned short* base, int row, int cb) {
        const int cs = cb ^ ((row & 7) << 4);
        return *reinterpret_cast<const bf16x8*>(
            reinterpret_cast<const char*>(base) + row * 128 + cs);
    };

    stage(0, 0);
    asm volatile("s_waitcnt vmcnt(0)" ::: "memory");
    __builtin_amdgcn_s_barrier();
    asm volatile("" ::: "memory");

    for (int T = 0; T < NKT; ++T) {
        if (T < NKT - 1) stage((T + 1) & 1, T + 1);
        const unsigned short* A = &As[T & 1][0];
        const unsigned short* B = &Bs[T & 1][0];
#pragma unroll
        for (int s = 0; s < 4; s++) {
            const int cb = s * 32 + half * 16;         // col byte (k-frag)
            const bf16x8 a0 = frg(A, wm + l31,      cb);
            const bf16x8 a1 = frg(A, wm + 32 + l31, cb);
            const bf16x8 b0 = frg(B, wn + l31,      cb);
            const bf16x8 b1 = frg(B, wn + 32 + l31, cb);
            acc[0][0] = __builtin_amdgcn_mfma_f32_32x32x16_bf16(a0, b0, acc[0][0], 0, 0, 0);
            acc[0][1] = __builtin_amdgcn_mfma_f32_32x32x16_bf16(a0, b1, acc[0][1], 0, 0, 0);
            acc[1][0] = __builtin_amdgcn_mfma_f32_32x32x16_bf16(a1, b0, acc[1][0], 0, 0, 0);
            acc[1][1] = __builtin_amdgcn_mfma_f32_32x32x16_bf16(a1, b1, acc[1][1], 0, 0, 0);
        }
        asm volatile("s_waitcnt vmcnt(0)" ::: "memory");
        __builtin_amdgcn_s_barrier();
        asm volatile("" ::: "memory");
    }

    // epilogue: C row = bm+wm+mi*32+(reg&3)+8*(reg>>2)+4*half; col = bn+wn+nj*32+l31
    if (proj < 2) {
        unsigned short* dst = (proj == 0) ? Qb : Kb;
#pragma unroll
        for (int nj = 0; nj < 2; nj++) {
            const int   e    = bn + wn + nj * 32 + l31;
            const int   h    = e >> 6, dd = e & 63;
            const float bias = bf2f(bias_p[e]);
#pragma unroll
            for (int mi = 0; mi < 2; mi++) {
#pragma unroll
                for (int reg = 0; reg < 16; reg++) {
                    const int mrow = bm + wm + mi * 32 + (reg & 3) + 8 * (reg >> 2) + 4 * half;
                    const int b = mrow >> 11, s = mrow & 2047;
                    dst[((size_t)(b * NH + h) * Sz + s) * DH + dd] = f2bf(acc[mi][nj][reg] + bias);
                }
            }
        }
    } else {
        // V transposed: regs 4g..4g+3 are 4 consecutive s -> one uint2 store
#pragma unroll
        for (int nj = 0; nj < 2; nj++) {
            const int   e    = bn + wn + nj * 32 + l31;
            const int   h    = e >> 6, dd = e & 63;
            const float bias = bf2f(bias_p[e]);
#pragma unroll
            for (int mi = 0; mi < 2; mi++) {
#pragma unroll
                for (int g = 0; g < 4; g++) {
                    const int m0 = bm + wm + mi * 32 + 8 * g + 4 * half;  // s-aligned to 4
                    const int b  = m0 >> 11, s0 = m0 & 2047;
                    const unsigned u0 = __float_as_uint(acc[mi][nj][4 * g + 0] + bias) + 0x8000u;
                    const unsigned u1 = __float_as_uint(acc[mi][nj][4 * g + 1] + bias) + 0x8000u;
                    const unsigned u2 = __float_as_uint(acc[mi][nj][4 * g + 2] + bias) + 0x8000u;
                    const unsigned u3 = __float_as_uint(acc[mi][nj][4 * g + 3] + bias) + 0x8000u;
                    uint2 pk;
                    pk.x = __builtin_amdgcn_perm(u1, u0, 0x07060302u);
                    pk.y = __builtin_amdgcn_perm(u3, u2, 0x07060302u);
                    *reinterpret_cast<uint2*>(
                        &Vtb[((size_t)(b * NH + h) * DH + dd) * Sz + s0]) = pk;
                }
            }
        }
    }
}

// ---------------------------------------------------------------------------
// Flash attention — R5-passing version, verbatim.
// ---------------------------------------------------------------------------
__global__ __launch_bounds__(512) void flash_attn(
    const unsigned short* __restrict__ Qb,    // [64][2048][64]
    const unsigned short* __restrict__ Kb,    // [64][2048][64]
    const unsigned short* __restrict__ Vtb,   // [64][64][2048]
    unsigned short* __restrict__ AOb)         // [4][2048][1024]
{
    __shared__ __align__(16) unsigned short Ks[64 * 72];    // [kv][d]
    __shared__ __align__(16) unsigned short Vs[64 * 72];    // [d][kv]
    __shared__ __align__(16) unsigned short Ps[128 * 72];   // [q][kv], wave-private rows

    const int tid  = threadIdx.x;
    const int w    = tid >> 6, lane = tid & 63;
    const int quad = lane >> 4, l15 = lane & 15;

    // XCD-locality remap: flat -> (bh, cA); bh % 8 == XCD id
    const int flat = (int)(blockIdx.y * gridDim.x + blockIdx.x);  // 0..511
    const int k8   = flat & 7;
    const int m    = flat >> 3;          // 0..63
    const int bh   = k8 + 8 * (m >> 3);  // 8 heads per XCD
    const int cA   = m & 7;

    const int srow = tid >> 3;            // 0..63  (512 threads)
    const int scc  = (tid & 7) * 8;       // 0..56
    const int hh = bh & 15, bb = bh >> 4;

    for (int pass = 0; pass < 2; pass++) {
        const int chunk = pass ? (15 - cA) : cA;
        const int qb = chunk * 128;
        const int qw = qb + w * 16;                  // wave's 16 q rows

        // Q fragment: B-operand layout (row=q=l15, k=quad*8+j)
        const size_t qbase = ((size_t)bh * Sz + qw + l15) * DH;
        const bf16x8 qf0 = *reinterpret_cast<const bf16x8*>(&Qb[qbase + quad * 8]);
        const bf16x8 qf1 = *reinterpret_cast<const bf16x8*>(&Qb[qbase + 32 + quad * 8]);

        f32x4 o[4];
#pragma unroll
        for (int jd = 0; jd < 4; jd++) o[jd] = f32x4{0.f, 0.f, 0.f, 0.f};
        float lsum = 0.f;

        const int n_kv = qb + 128;                   // multiple of 128

        auto compute = [&](int kb) {
            const bool need_mask = (kb + 64 > qw);
#pragma unroll
            for (int j = 0; j < 4; j++) {
                const bf16x8 kf0 = *reinterpret_cast<const bf16x8*>(&Ks[(j * 16 + l15) * 72 + quad * 8]);
                const bf16x8 kf1 = *reinterpret_cast<const bf16x8*>(&Ks[(j * 16 + l15) * 72 + 32 + quad * 8]);
                f32x4 st = f32x4{0.f, 0.f, 0.f, 0.f};
                st = __builtin_amdgcn_mfma_f32_16x16x32_bf16(kf0, qf0, st, 0, 0, 0);
                st = __builtin_amdgcn_mfma_f32_16x16x32_bf16(kf1, qf1, st, 0, 0, 0);
                // p = exp(S/8) = exp2(S * 0.125*log2(e)); causal mask via select
                const int qa = qw + l15;
                float p[4];
#pragma unroll
                for (int r = 0; r < 4; r++) {
                    float e = __builtin_amdgcn_exp2f(st[r] * 0.18033688011f);
                    if (need_mask) {
                        const int kv = kb + j * 16 + quad * 4 + r;
                        e = (kv <= qa) ? e : 0.f;
                    }
                    p[r] = e;
                }
                lsum += (p[0] + p[1]) + (p[2] + p[3]);
                const unsigned u0 = __float_as_uint(p[0]) + 0x8000u;
                const unsigned u1 = __float_as_uint(p[1]) + 0x8000u;
                const unsigned u2 = __float_as_uint(p[2]) + 0x8000u;
                const unsigned u3 = __float_as_uint(p[3]) + 0x8000u;
                const unsigned pk0 = __builtin_amdgcn_perm(u1, u0, 0x07060302u);
                const unsigned pk1 = __builtin_amdgcn_perm(u3, u2, 0x07060302u);
                const int prow = (w * 16 + l15) * 72 + j * 16 + quad * 4;
                *reinterpret_cast<unsigned*>(&Ps[prow])     = pk0;
                *reinterpret_cast<unsigned*>(&Ps[prow + 2]) = pk1;
            }

            // wave-private Ps rows: in-wave drain only, no barrier
            asm volatile("s_waitcnt lgkmcnt(0)" ::: "memory");

            const bf16x8 pf0 = *reinterpret_cast<const bf16x8*>(&Ps[(w * 16 + l15) * 72 + quad * 8]);
            const bf16x8 pf1 = *reinterpret_cast<const bf16x8*>(&Ps[(w * 16 + l15) * 72 + 32 + quad * 8]);
#pragma unroll
            for (int jd = 0; jd < 4; jd++) {
                const bf16x8 vf0 = *reinterpret_cast<const bf16x8*>(&Vs[(jd * 16 + l15) * 72 + quad * 8]);
                const bf16x8 vf1 = *reinterpret_cast<const bf16x8*>(&Vs[(jd * 16 + l15) * 72 + 32 + quad * 8]);
                o[jd] = __builtin_amdgcn_mfma_f32_16x16x32_bf16(pf0, vf0, o[jd], 0, 0, 0);
                o[jd] = __builtin_amdgcn_mfma_f32_16x16x32_bf16(pf1, vf1, o[jd], 0, 0, 0);
            }
        };

        // prologue: prefetch tile 0 into registers
        uint4 kr0 = *reinterpret_cast<const uint4*>(&Kb[((size_t)bh * Sz + srow) * DH + scc]);
        uint4 vr0 = *reinterpret_cast<const uint4*>(&Vtb[((size_t)bh * DH + srow) * Sz + scc]);
        uint4 kr1, vr1;

        for (int kb = 0; kb < n_kv; kb += 128) {
            // ---------------- tile kb (regs kr0/vr0) ----------------
            __syncthreads();    // prev compute done; drains kr0/vr0 (used now)
            *reinterpret_cast<uint4*>(&Ks[srow * 72 + scc]) = kr0;
            *reinterpret_cast<uint4*>(&Vs[srow * 72 + scc]) = vr0;
            // prefetch tile kb+64 (always exists: n_kv is a multiple of 128)
            kr1 = *reinterpret_cast<const uint4*>(&Kb[((size_t)bh * Sz + kb + 64 + srow) * DH + scc]);
            vr1 = *reinterpret_cast<const uint4*>(&Vtb[((size_t)bh * DH + srow) * Sz + kb + 64 + scc]);
            asm volatile("s_waitcnt lgkmcnt(0)" ::: "memory");
            __builtin_amdgcn_s_barrier();             // raw: keep prefetch in flight
            asm volatile("" ::: "memory");
            if (kb <= qw + 15) compute(kb);

            // ---------------- tile kb+64 (regs kr1/vr1) ----------------
            __syncthreads();
            *reinterpret_cast<uint4*>(&Ks[srow * 72 + scc]) = kr1;
            *reinterpret_cast<uint4*>(&Vs[srow * 72 + scc]) = vr1;
            if (kb + 128 < n_kv) {
                kr0 = *reinterpret_cast<const uint4*>(&Kb[((size_t)bh * Sz + kb + 128 + srow) * DH + scc]);
                vr0 = *reinterpret_cast<const uint4*>(&Vtb[((size_t)bh * DH + srow) * Sz + kb + 128 + scc]);
            }
            asm volatile("s_waitcnt lgkmcnt(0)" ::: "memory");
            __builtin_amdgcn_s_barrier();
            asm volatile("" ::: "memory");
            if (kb + 64 <= qw + 15) compute(kb + 64);
        }

        // reduce lsum across quads (lane holds partial for q = qw + l15)
        lsum += __shfl_xor(lsum, 16);
        lsum += __shfl_xor(lsum, 32);

        // write AO[b][s][h*64+d]; o[jd][r] is q-row quad*4+r, col jd*16+l15
        float linv[4];
#pragma unroll
        for (int r = 0; r < 4; r++)
            linv[r] = 1.0f / __shfl(lsum, quad * 4 + r);
#pragma unroll
        for (int jd = 0; jd < 4; jd++) {
#pragma unroll
            for (int r = 0; r < 4; r++) {
                const int s = qw + quad * 4 + r;
                AOb[((size_t)(bb * Sz + s)) * DM + hh * DH + jd * 16 + l15] =
                    f2bf(o[jd][r] * linv[r]);
            }
        }
    }
}

// ---------------------------------------------------------------------------
// Output projection: out = AO[8192,1024] @ Wo[1024,1024]^T + bo
// Same R12 32x32 chassis. grid: (8,64) = 512 blocks x 256 threads.
// ---------------------------------------------------------------------------
__global__ __launch_bounds__(256, 2) void gemm_out(
    const unsigned short* __restrict__ Ain,
    const unsigned short* __restrict__ W,
    const unsigned short* __restrict__ bo,
    void* __restrict__ outv,
    const int* __restrict__ flagp)
{
    __shared__ __align__(16) unsigned short As[2][128 * 64];
    __shared__ __align__(16) unsigned short Bs[2][128 * 64];

    const int tid  = threadIdx.x;
    const int w    = tid >> 6, lane = tid & 63;
    const int l31  = lane & 31, half = lane >> 5;
    const int wm   = (w & 1) * 64, wn = (w >> 1) * 64;

    // XCD-locality remap (R5): flat -> (bm, bn)
    const int flat = (int)(blockIdx.y * gridDim.x + blockIdx.x);  // 0..511
    const int k8   = flat & 7;
    const int m    = flat >> 3;          // 0..63
    const int bm   = (k8 * 8 + (m >> 3)) * 128;
    const int bn   = (m & 7) * 128;

    const unsigned short* Abase = Ain + (size_t)bm * DM;
    const unsigned short* Bbase = W   + (size_t)bn * DM;

    const int sr8 = lane >> 3;
    const int sce = ((lane & 7) ^ sr8) * 8;

    f32x16 acc[2][2];
#pragma unroll
    for (int i = 0; i < 2; i++)
#pragma unroll
        for (int j = 0; j < 2; j++)
#pragma unroll
            for (int e = 0; e < 16; e++)
                acc[i][j][e] = 0.f;

    auto stage = [&](int buf, int kt) {
        const int kc = kt * 64;
#pragma unroll
        for (int t = 0; t < 4; t++) {
            const int r = w * 32 + t * 8;
            GLD_LDS16(&Abase[(size_t)(r + sr8) * DM + kc + sce], &As[buf][r * 64]);
            GLD_LDS16(&Bbase[(size_t)(r + sr8) * DM + kc + sce], &Bs[buf][r * 64]);
        }
    };

    auto frg = [&](const unsigned short* base, int row, int cb) {
        const int cs = cb ^ ((row & 7) << 4);
        return *reinterpret_cast<const bf16x8*>(
            reinterpret_cast<const char*>(base) + row * 128 + cs);
    };

    stage(0, 0);
    asm volatile("s_waitcnt vmcnt(0)" ::: "memory");
    __builtin_amdgcn_s_barrier();
    asm volatile("" ::: "memory");

    for (int T = 0; T < NKT; ++T) {
        if (T < NKT - 1) stage((T + 1) & 1, T + 1);
        const unsigned short* A = &As[T & 1][0];
        const unsigned short* B = &Bs[T & 1][0];
#pragma unroll
        for (int s = 0; s < 4; s++) {
            const int cb = s * 32 + half * 16;
            const bf16x8 a0 = frg(A, wm + l31,      cb);
            const bf16x8 a1 = frg(A, wm + 32 + l31, cb);
            const bf16x8 b0 = frg(B, wn + l31,      cb);
            const bf16x8 b1 = frg(B, wn + 32 + l31, cb);
            acc[0][0] = __builtin_amdgcn_mfma_f32_32x32x16_bf16(a0, b0, acc[0][0], 0, 0, 0);
            acc[0][1] = __builtin_amdgcn_mfma_f32_32x32x16_bf16(a0, b1, acc[0][1], 0, 0, 0);
            acc[1][0] = __builtin_amdgcn_mfma_f32_32x32x16_bf16(a1, b0, acc[1][0], 0, 0, 0);
            acc[1][1] = __builtin_amdgcn_mfma_f32_32x32x16_bf16(a1, b1, acc[1][1], 0, 0, 0);
        }
        asm volatile("s_waitcnt vmcnt(0)" ::: "memory");
        __builtin_amdgcn_s_barrier();
        asm volatile("" ::: "memory");
    }

    const int flag = *flagp;
    float*          outf = (float*)outv;
    unsigned short* outh = (unsigned short*)outv;
#pragma unroll
    for (int nj = 0; nj < 2; nj++) {
        const int   e    = bn + wn + nj * 32 + l31;
        const float bias = bf2f(bo[e]);
#pragma unroll
        for (int mi = 0; mi < 2; mi++) {
#pragma unroll
            for (int reg = 0; reg < 16; reg++) {
                const int   mrow = bm + wm + mi * 32 + (reg & 3) + 8 * (reg >> 2) + 4 * half;
                const float v = acc[mi][nj][reg] + bias;
                if (flag) outf[(size_t)mrow * DM + e] = v;
                else      outh[(size_t)mrow * DM + e] = f2bf(v);
            }
        }
    }
}

// ---------------------------------------------------------------------------
extern "C" void kernel_launch(void* const* d_in, const int* in_sizes, int n_in,
                              void* d_out, int out_size, void* d_ws, size_t ws_size,
                              hipStream_t stream) {
    // Bind inputs by ELEMENT COUNT (dtype/mask-presence robust)
    const void* x = nullptr;
    const void* Wsrc[4] = {nullptr, nullptr, nullptr, nullptr};
    const void* bsrc[4] = {nullptr, nullptr, nullptr, nullptr};
    int nw = 0, nb = 0;
    for (int i = 0; i < n_in; i++) {
        const int sz = in_sizes[i];
        if (sz == Bz * Sz * DM)            { if (!x) x = d_in[i]; }
        else if (sz == DM * DM)            { if (nw < 4) Wsrc[nw++] = d_in[i]; }
        else if (sz == DM)                 { if (nb < 4) bsrc[nb++] = d_in[i]; }
    }

    char* wsb = (char*)d_ws;
    int*  flagp = (int*)wsb;
    unsigned short* Xc  = (unsigned short*)(wsb + 16);
    const size_t NX = (size_t)Bz * Sz * DM;       // 8,388,608
    const size_t NW = (size_t)DM * DM;            // 1,048,576
    unsigned short* Wc0 = Xc  + NX;
    unsigned short* Wc1 = Wc0 + NW;
    unsigned short* Wc2 = Wc1 + NW;
    unsigned short* Wc3 = Wc2 + NW;
    unsigned short* bc0 = Wc3 + NW;
    unsigned short* bc1 = bc0 + DM;
    unsigned short* bc2 = bc1 + DM;
    unsigned short* bc3 = bc2 + DM;
    unsigned short* Qb  = bc3 + DM;
    const size_t SZ = (size_t)Bz * NH * Sz * DH;  // 8,388,608
    unsigned short* Kb  = Qb  + SZ;
    unsigned short* Vtb = Kb  + SZ;
    unsigned short* AOb = Vtb + SZ;

    detect_dtype<<<1, 64, 0, stream>>>((const unsigned short*)x, flagp);
    convert_inputs<<<dim3(512, 9), 256, 0, stream>>>(
        x, Wsrc[0], Wsrc[1], Wsrc[2], Wsrc[3],
        bsrc[0], bsrc[1], bsrc[2], bsrc[3],
        Xc, Wc0, Wc1, Wc2, Wc3, bc0, bc1, bc2, bc3, flagp);

    gemm_qkv <<<dim3(24, 64), 256, 0, stream>>>(Xc, Wc0, Wc1, Wc2, bc0, bc1, bc2, Qb, Kb, Vtb);
    flash_attn<<<dim3(8, 64), 512, 0, stream>>>(Qb, Kb, Vtb, AOb);
    gemm_out <<<dim3(8, 64), 256, 0, stream>>>(AOb, Wc3, bc3, d_out, flagp);
}

// Round 9
// 279.437 us; speedup vs baseline: 1.1842x; 1.0318x over previous
//
#include <hip/hip_runtime.h>
#include <stdint.h>

#define NH 16
#define DH 64
#define DM 1024
#define Bz 4
#define Sz 2048
#define NKT 16   // K tiles of 64

typedef __bf16 bf16x8 __attribute__((ext_vector_type(8)));
typedef float f32x4 __attribute__((ext_vector_type(4)));
typedef float f32x16 __attribute__((ext_vector_type(16)));

// async global(16B/lane) -> LDS (wave-uniform base + lane*16)
#define GLD_LDS16(gsrc, ldst)                                             \
    __builtin_amdgcn_global_load_lds(                                     \
        (const __attribute__((address_space(1))) void*)(gsrc),            \
        (__attribute__((address_space(3))) void*)(ldst), 16, 0, 0)

__device__ __forceinline__ unsigned short f2bf(float f) {
    unsigned u = __float_as_uint(f);
    u += 0x7FFFu + ((u >> 16) & 1u);          // RNE
    return (unsigned short)(u >> 16);
}
__device__ __forceinline__ float bf2f(unsigned short h) {
    return __uint_as_float(((unsigned)h) << 16);
}
__device__ __forceinline__ unsigned pack2bf(float a, float b) {
    return (unsigned)f2bf(a) | ((unsigned)f2bf(b) << 16);
}

// ---------------------------------------------------------------------------
// Dtype detection (f32 vs bf16 storage). flag=1 => f32.
// ---------------------------------------------------------------------------
__global__ void detect_dtype(const unsigned short* __restrict__ xs,
                             int* __restrict__ flagp)
{
    const int t = threadIdx.x;          // 64 threads, 1 block
    int cnt = 0;
    for (int i = 0; i < 64; i++) {
        const unsigned short h = xs[(t * 64 + i) * 2];
        const int e = (h >> 7) & 0xFF;
        if (h != 0 && e >= 100 && e <= 130) cnt++;
    }
#pragma unroll
    for (int off = 32; off >= 1; off >>= 1)
        cnt += __shfl_xor(cnt, off);
    if (t == 0) *flagp = (cnt < 2048) ? 1 : 0;
}

// ---------------------------------------------------------------------------
// Canonicalize 9 tensors into bf16 workspace buffers.
// R13: 8 elem/thread, 16B uint4 stores (was 2x 4B ushort2 — G13 fix).
// ---------------------------------------------------------------------------
__global__ __launch_bounds__(256) void convert_inputs(
    const void* s0, const void* s1, const void* s2, const void* s3,
    const void* s4, const void* s5, const void* s6, const void* s7,
    const void* s8,
    unsigned short* d0, unsigned short* d1, unsigned short* d2,
    unsigned short* d3, unsigned short* d4, unsigned short* d5,
    unsigned short* d6, unsigned short* d7, unsigned short* d8,
    const int* __restrict__ flagp)
{
    const void* s; unsigned short* d; int n;
    switch (blockIdx.y) {
        case 0: s = s0; d = d0; n = Bz * Sz * DM; break;   // x
        case 1: s = s1; d = d1; n = DM * DM; break;        // Wq
        case 2: s = s2; d = d2; n = DM * DM; break;        // Wk
        case 3: s = s3; d = d3; n = DM * DM; break;        // Wv
        case 4: s = s4; d = d4; n = DM * DM; break;        // Wo
        case 5: s = s5; d = d5; n = DM; break;             // bq
        case 6: s = s6; d = d6; n = DM; break;             // bk
        case 7: s = s7; d = d7; n = DM; break;             // bv
        default: s = s8; d = d8; n = DM; break;            // bo
    }
    const int flag   = *flagp;
    const int stride = gridDim.x * blockDim.x * 8;
    const int base   = (blockIdx.x * blockDim.x + threadIdx.x) * 8;
    if (flag) {
        const float* sf = (const float*)s;
        for (int i = base; i < n; i += stride) {
            const float4 v0 = *reinterpret_cast<const float4*>(&sf[i]);
            const float4 v1 = *reinterpret_cast<const float4*>(&sf[i + 4]);
            uint4 o;
            o.x = pack2bf(v0.x, v0.y);
            o.y = pack2bf(v0.z, v0.w);
            o.z = pack2bf(v1.x, v1.y);
            o.w = pack2bf(v1.z, v1.w);
            *reinterpret_cast<uint4*>(&d[i]) = o;
        }
    } else {
        const unsigned short* sh = (const unsigned short*)s;
        for (int i = base; i < n; i += stride)
            *reinterpret_cast<uint4*>(&d[i]) = *reinterpret_cast<const uint4*>(&sh[i]);
    }
}

// ===========================================================================
// R12 GEMM chassis (kept for qkv — proven 81.4us @ R8): 128x128 tile,
// 32x32x16 MFMA, BK=64, [128][64] LDS, XOR swizzle both-sides (T21),
// double-buffer + drain. C layout (m74/m101): col=lane&31,
// row=(reg&3)+8*(reg>>2)+4*(lane>>5).
// ===========================================================================

// ---------------------------------------------------------------------------
// QKV projection — UNCHANGED from R8 (proven 81.4us).
// ---------------------------------------------------------------------------
__global__ __launch_bounds__(256, 2) void gemm_qkv(
    const unsigned short* __restrict__ X,
    const unsigned short* __restrict__ Wq,
    const unsigned short* __restrict__ Wk,
    const unsigned short* __restrict__ Wv,
    const unsigned short* __restrict__ bq,
    const unsigned short* __restrict__ bk,
    const unsigned short* __restrict__ bv,
    unsigned short* __restrict__ Qb,
    unsigned short* __restrict__ Kb,
    unsigned short* __restrict__ Vtb)
{
    __shared__ __align__(16) unsigned short As[2][128 * 64];   // 2 x 16 KB
    __shared__ __align__(16) unsigned short Bs[2][128 * 64];   // 2 x 16 KB

    const int tid  = threadIdx.x;
    const int w    = tid >> 6, lane = tid & 63;
    const int l31  = lane & 31, half = lane >> 5;
    const int wm   = (w & 1) * 64, wn = (w >> 1) * 64;

    // XCD-locality remap (R5): flat -> (proj, bm, bn)
    const int flat = (int)(blockIdx.y * gridDim.x + blockIdx.x);  // 0..1535
    const int k8   = flat & 7;
    const int m    = flat >> 3;         // 0..191
    const int proj = m >> 6;            // 0..2
    const int mm   = m & 63;            // 0..63
    const int bm   = (k8 * 8 + (mm >> 3)) * 128;
    const int bn   = (mm & 7) * 128;

    const unsigned short* W      = proj == 0 ? Wq : (proj == 1 ? Wk : Wv);
    const unsigned short* bias_p = proj == 0 ? bq : (proj == 1 ? bk : bv);
    const unsigned short* Abase  = X + (size_t)bm * DM;
    const unsigned short* Bbase  = W + (size_t)bn * DM;

    const int sr8 = lane >> 3;                         // 0..7 (row in group)
    const int sce = ((lane & 7) ^ sr8) * 8;            // pre-swizzled col elem

    f32x16 acc[2][2];
#pragma unroll
    for (int i = 0; i < 2; i++)
#pragma unroll
        for (int j = 0; j < 2; j++)
#pragma unroll
            for (int e = 0; e < 16; e++)
                acc[i][j][e] = 0.f;

    auto stage = [&](int buf, int kt) {
        const int kc = kt * 64;
#pragma unroll
        for (int t = 0; t < 4; t++) {
            const int r = w * 32 + t * 8;
            GLD_LDS16(&Abase[(size_t)(r + sr8) * DM + kc + sce], &As[buf][r * 64]);
            GLD_LDS16(&Bbase[(size_t)(r + sr8) * DM + kc + sce], &Bs[buf][r * 64]);
        }
    };

    auto frg = [&](const unsigned short* base, int row, int cb) {
        const int cs = cb ^ ((row & 7) << 4);
        return *reinterpret_cast<const bf16x8*>(
            reinterpret_cast<const char*>(base) + row * 128 + cs);
    };

    stage(0, 0);
    asm volatile("s_waitcnt vmcnt(0)" ::: "memory");
    __builtin_amdgcn_s_barrier();
    asm volatile("" ::: "memory");

    for (int T = 0; T < NKT; ++T) {
        if (T < NKT - 1) stage((T + 1) & 1, T + 1);
        const unsigned short* A = &As[T & 1][0];
        const unsigned short* B = &Bs[T & 1][0];
#pragma unroll
        for (int s = 0; s < 4; s++) {
            const int cb = s * 32 + half * 16;         // col byte (k-frag)
            const bf16x8 a0 = frg(A, wm + l31,      cb);
            const bf16x8 a1 = frg(A, wm + 32 + l31, cb);
            const bf16x8 b0 = frg(B, wn + l31,      cb);
            const bf16x8 b1 = frg(B, wn + 32 + l31, cb);
            acc[0][0] = __builtin_amdgcn_mfma_f32_32x32x16_bf16(a0, b0, acc[0][0], 0, 0, 0);
            acc[0][1] = __builtin_amdgcn_mfma_f32_32x32x16_bf16(a0, b1, acc[0][1], 0, 0, 0);
            acc[1][0] = __builtin_amdgcn_mfma_f32_32x32x16_bf16(a1, b0, acc[1][0], 0, 0, 0);
            acc[1][1] = __builtin_amdgcn_mfma_f32_32x32x16_bf16(a1, b1, acc[1][1], 0, 0, 0);
        }
        asm volatile("s_waitcnt vmcnt(0)" ::: "memory");
        __builtin_amdgcn_s_barrier();
        asm volatile("" ::: "memory");
    }

    // epilogue: C row = bm+wm+mi*32+(reg&3)+8*(reg>>2)+4*half; col = bn+wn+nj*32+l31
    if (proj < 2) {
        unsigned short* dst = (proj == 0) ? Qb : Kb;
#pragma unroll
        for (int nj = 0; nj < 2; nj++) {
            const int   e    = bn + wn + nj * 32 + l31;
            const int   h    = e >> 6, dd = e & 63;
            const float bias = bf2f(bias_p[e]);
#pragma unroll
            for (int mi = 0; mi < 2; mi++) {
#pragma unroll
                for (int reg = 0; reg < 16; reg++) {
                    const int mrow = bm + wm + mi * 32 + (reg & 3) + 8 * (reg >> 2) + 4 * half;
                    const int b = mrow >> 11, s = mrow & 2047;
                    dst[((size_t)(b * NH + h) * Sz + s) * DH + dd] = f2bf(acc[mi][nj][reg] + bias);
                }
            }
        }
    } else {
        // V transposed: regs 4g..4g+3 are 4 consecutive s -> one uint2 store
#pragma unroll
        for (int nj = 0; nj < 2; nj++) {
            const int   e    = bn + wn + nj * 32 + l31;
            const int   h    = e >> 6, dd = e & 63;
            const float bias = bf2f(bias_p[e]);
#pragma unroll
            for (int mi = 0; mi < 2; mi++) {
#pragma unroll
                for (int g = 0; g < 4; g++) {
                    const int m0 = bm + wm + mi * 32 + 8 * g + 4 * half;  // s-aligned to 4
                    const int b  = m0 >> 11, s0 = m0 & 2047;
                    const unsigned u0 = __float_as_uint(acc[mi][nj][4 * g + 0] + bias) + 0x8000u;
                    const unsigned u1 = __float_as_uint(acc[mi][nj][4 * g + 1] + bias) + 0x8000u;
                    const unsigned u2 = __float_as_uint(acc[mi][nj][4 * g + 2] + bias) + 0x8000u;
                    const unsigned u3 = __float_as_uint(acc[mi][nj][4 * g + 3] + bias) + 0x8000u;
                    uint2 pk;
                    pk.x = __builtin_amdgcn_perm(u1, u0, 0x07060302u);
                    pk.y = __builtin_amdgcn_perm(u3, u2, 0x07060302u);
                    *reinterpret_cast<uint2*>(
                        &Vtb[((size_t)(b * NH + h) * DH + dd) * Sz + s0]) = pk;
                }
            }
        }
    }
}

// ---------------------------------------------------------------------------
// Flash attention — R5/R8 structure; R13: K/V staged 128-kv at a time
// (one sync pair per 128 kv instead of two — halves barrier count).
// Ks [128][72]; Vs [64][136] (136 = 128+8, same mod-32-bank profile as 72).
// T14 reg-prefetch kept: next 128-block loaded into the same regs right
// after the LDS writes consume them; raw s_barrier after lgkmcnt(0) keeps
// those global loads in flight across compute.
// ---------------------------------------------------------------------------
__global__ __launch_bounds__(512) void flash_attn(
    const unsigned short* __restrict__ Qb,    // [64][2048][64]
    const unsigned short* __restrict__ Kb,    // [64][2048][64]
    const unsigned short* __restrict__ Vtb,   // [64][64][2048]
    unsigned short* __restrict__ AOb)         // [4][2048][1024]
{
    __shared__ __align__(16) unsigned short Ks[128 * 72];   // [kv 0..127][d]
    __shared__ __align__(16) unsigned short Vs[64 * 136];   // [d][kv 0..127]
    __shared__ __align__(16) unsigned short Ps[128 * 72];   // [q][kv], wave-private rows

    const int tid  = threadIdx.x;
    const int w    = tid >> 6, lane = tid & 63;
    const int quad = lane >> 4, l15 = lane & 15;

    // XCD-locality remap: flat -> (bh, cA); bh % 8 == XCD id
    const int flat = (int)(blockIdx.y * gridDim.x + blockIdx.x);  // 0..511
    const int k8   = flat & 7;
    const int m    = flat >> 3;          // 0..63
    const int bh   = k8 + 8 * (m >> 3);  // 8 heads per XCD
    const int cA   = m & 7;

    const int srow = tid >> 3;            // 0..63  (512 threads)
    const int scc  = (tid & 7) * 8;       // 0..56
    const int hh = bh & 15, bb = bh >> 4;

    for (int pass = 0; pass < 2; pass++) {
        const int chunk = pass ? (15 - cA) : cA;
        const int qb = chunk * 128;
        const int qw = qb + w * 16;                  // wave's 16 q rows

        // Q fragment: B-operand layout (row=q=l15, k=quad*8+j)
        const size_t qbase = ((size_t)bh * Sz + qw + l15) * DH;
        const bf16x8 qf0 = *reinterpret_cast<const bf16x8*>(&Qb[qbase + quad * 8]);
        const bf16x8 qf1 = *reinterpret_cast<const bf16x8*>(&Qb[qbase + 32 + quad * 8]);

        f32x4 o[4];
#pragma unroll
        for (int jd = 0; jd < 4; jd++) o[jd] = f32x4{0.f, 0.f, 0.f, 0.f};
        float lsum = 0.f;

        const int n_kv = qb + 128;                   // multiple of 128

        // compute one 64-kv tile; kbe = global kv base, off = kbe & 127 (0/64)
        auto compute = [&](int kbe) {
            const int  off       = kbe & 127;
            const bool need_mask = (kbe + 64 > qw);
#pragma unroll
            for (int j = 0; j < 4; j++) {
                const bf16x8 kf0 = *reinterpret_cast<const bf16x8*>(&Ks[(off + j * 16 + l15) * 72 + quad * 8]);
                const bf16x8 kf1 = *reinterpret_cast<const bf16x8*>(&Ks[(off + j * 16 + l15) * 72 + 32 + quad * 8]);
                f32x4 st = f32x4{0.f, 0.f, 0.f, 0.f};
                st = __builtin_amdgcn_mfma_f32_16x16x32_bf16(kf0, qf0, st, 0, 0, 0);
                st = __builtin_amdgcn_mfma_f32_16x16x32_bf16(kf1, qf1, st, 0, 0, 0);
                // p = exp(S/8) = exp2(S * 0.125*log2(e)); causal mask via select
                const int qa = qw + l15;
                float p[4];
#pragma unroll
                for (int r = 0; r < 4; r++) {
                    float e = __builtin_amdgcn_exp2f(st[r] * 0.18033688011f);
                    if (need_mask) {
                        const int kv = kbe + j * 16 + quad * 4 + r;
                        e = (kv <= qa) ? e : 0.f;
                    }
                    p[r] = e;
                }
                lsum += (p[0] + p[1]) + (p[2] + p[3]);
                const unsigned u0 = __float_as_uint(p[0]) + 0x8000u;
                const unsigned u1 = __float_as_uint(p[1]) + 0x8000u;
                const unsigned u2 = __float_as_uint(p[2]) + 0x8000u;
                const unsigned u3 = __float_as_uint(p[3]) + 0x8000u;
                const unsigned pk0 = __builtin_amdgcn_perm(u1, u0, 0x07060302u);
                const unsigned pk1 = __builtin_amdgcn_perm(u3, u2, 0x07060302u);
                const int prow = (w * 16 + l15) * 72 + j * 16 + quad * 4;
                *reinterpret_cast<unsigned*>(&Ps[prow])     = pk0;
                *reinterpret_cast<unsigned*>(&Ps[prow + 2]) = pk1;
            }

            // wave-private Ps rows: in-wave drain only, no barrier
            asm volatile("s_waitcnt lgkmcnt(0)" ::: "memory");

            const bf16x8 pf0 = *reinterpret_cast<const bf16x8*>(&Ps[(w * 16 + l15) * 72 + quad * 8]);
            const bf16x8 pf1 = *reinterpret_cast<const bf16x8*>(&Ps[(w * 16 + l15) * 72 + 32 + quad * 8]);
#pragma unroll
            for (int jd = 0; jd < 4; jd++) {
                const bf16x8 vf0 = *reinterpret_cast<const bf16x8*>(&Vs[(jd * 16 + l15) * 136 + off + quad * 8]);
                const bf16x8 vf1 = *reinterpret_cast<const bf16x8*>(&Vs[(jd * 16 + l15) * 136 + off + 32 + quad * 8]);
                o[jd] = __builtin_amdgcn_mfma_f32_16x16x32_bf16(pf0, vf0, o[jd], 0, 0, 0);
                o[jd] = __builtin_amdgcn_mfma_f32_16x16x32_bf16(pf1, vf1, o[jd], 0, 0, 0);
            }
        };

        // prologue: prefetch 128-block 0 into registers
        uint4 kr0 = *reinterpret_cast<const uint4*>(&Kb[((size_t)bh * Sz + srow) * DH + scc]);
        uint4 kr1 = *reinterpret_cast<const uint4*>(&Kb[((size_t)bh * Sz + 64 + srow) * DH + scc]);
        uint4 vr0 = *reinterpret_cast<const uint4*>(&Vtb[((size_t)bh * DH + srow) * Sz + scc]);
        uint4 vr1 = *reinterpret_cast<const uint4*>(&Vtb[((size_t)bh * DH + srow) * Sz + 64 + scc]);

        for (int kb = 0; kb < n_kv; kb += 128) {
            __syncthreads();    // prev compute done (also drains the prefetch, used now)
            *reinterpret_cast<uint4*>(&Ks[srow * 72 + scc])        = kr0;
            *reinterpret_cast<uint4*>(&Ks[(64 + srow) * 72 + scc]) = kr1;
            *reinterpret_cast<uint4*>(&Vs[srow * 136 + scc])       = vr0;
            *reinterpret_cast<uint4*>(&Vs[srow * 136 + 64 + scc])  = vr1;
            if (kb + 128 < n_kv) {   // prefetch next 128-block into same regs
                kr0 = *reinterpret_cast<const uint4*>(&Kb[((size_t)bh * Sz + kb + 128 + srow) * DH + scc]);
                kr1 = *reinterpret_cast<const uint4*>(&Kb[((size_t)bh * Sz + kb + 192 + srow) * DH + scc]);
                vr0 = *reinterpret_cast<const uint4*>(&Vtb[((size_t)bh * DH + srow) * Sz + kb + 128 + scc]);
                vr1 = *reinterpret_cast<const uint4*>(&Vtb[((size_t)bh * DH + srow) * Sz + kb + 192 + scc]);
            }
            asm volatile("s_waitcnt lgkmcnt(0)" ::: "memory");
            __builtin_amdgcn_s_barrier();             // raw: keep prefetch in flight
            asm volatile("" ::: "memory");
            if (kb <= qw + 15)      compute(kb);
            if (kb + 64 <= qw + 15) compute(kb + 64);
        }

        // reduce lsum across quads (lane holds partial for q = qw + l15)
        lsum += __shfl_xor(lsum, 16);
        lsum += __shfl_xor(lsum, 32);

        // write AO[b][s][h*64+d]; o[jd][r] is q-row quad*4+r, col jd*16+l15
        float linv[4];
#pragma unroll
        for (int r = 0; r < 4; r++)
            linv[r] = 1.0f / __shfl(lsum, quad * 4 + r);
#pragma unroll
        for (int jd = 0; jd < 4; jd++) {
#pragma unroll
            for (int r = 0; r < 4; r++) {
                const int s = qw + quad * 4 + r;
                AOb[((size_t)(bb * Sz + s)) * DM + hh * DH + jd * 16 + l15] =
                    f2bf(o[jd][r] * linv[r]);
            }
        }
    }
}

// ---------------------------------------------------------------------------
// Output projection: out = AO[8192,1024] @ Wo[1024,1024]^T + bo
// R13: SINGLE-buffered 32KB LDS + launch_bounds(256,4) -> 4 blocks/CU.
// Theory: out's A (AOb) is cold/scattered across XCDs after flash ->
// L3-latency-bound; at 2 blocks/CU TLP is too thin. 2x blocks hides it.
// Loop: stage(T) -> vmcnt(0)+barrier -> compute(T) -> barrier (WAR guard).
// ---------------------------------------------------------------------------
__global__ __launch_bounds__(256, 4) void gemm_out(
    const unsigned short* __restrict__ Ain,
    const unsigned short* __restrict__ W,
    const unsigned short* __restrict__ bo,
    void* __restrict__ outv,
    const int* __restrict__ flagp)
{
    __shared__ __align__(16) unsigned short As[128 * 64];   // 16 KB
    __shared__ __align__(16) unsigned short Bs[128 * 64];   // 16 KB

    const int tid  = threadIdx.x;
    const int w    = tid >> 6, lane = tid & 63;
    const int l31  = lane & 31, half = lane >> 5;
    const int wm   = (w & 1) * 64, wn = (w >> 1) * 64;

    // XCD-locality remap (R5): flat -> (bm, bn)
    const int flat = (int)(blockIdx.y * gridDim.x + blockIdx.x);  // 0..511
    const int k8   = flat & 7;
    const int m    = flat >> 3;          // 0..63
    const int bm   = (k8 * 8 + (m >> 3)) * 128;
    const int bn   = (m & 7) * 128;

    const unsigned short* Abase = Ain + (size_t)bm * DM;
    const unsigned short* Bbase = W   + (size_t)bn * DM;

    const int sr8 = lane >> 3;
    const int sce = ((lane & 7) ^ sr8) * 8;

    f32x16 acc[2][2];
#pragma unroll
    for (int i = 0; i < 2; i++)
#pragma unroll
        for (int j = 0; j < 2; j++)
#pragma unroll
            for (int e = 0; e < 16; e++)
                acc[i][j][e] = 0.f;

    auto stage = [&](int kt) {
        const int kc = kt * 64;
#pragma unroll
        for (int t = 0; t < 4; t++) {
            const int r = w * 32 + t * 8;
            GLD_LDS16(&Abase[(size_t)(r + sr8) * DM + kc + sce], &As[r * 64]);
            GLD_LDS16(&Bbase[(size_t)(r + sr8) * DM + kc + sce], &Bs[r * 64]);
        }
    };

    auto frg = [&](const unsigned short* base, int row, int cb) {
        const int cs = cb ^ ((row & 7) << 4);
        return *reinterpret_cast<const bf16x8*>(
            reinterpret_cast<const char*>(base) + row * 128 + cs);
    };

    for (int T = 0; T < NKT; ++T) {
        stage(T);
        asm volatile("s_waitcnt vmcnt(0)" ::: "memory");
        __builtin_amdgcn_s_barrier();
        asm volatile("" ::: "memory");
#pragma unroll
        for (int s = 0; s < 4; s++) {
            const int cb = s * 32 + half * 16;
            const bf16x8 a0 = frg(As, wm + l31,      cb);
            const bf16x8 a1 = frg(As, wm + 32 + l31, cb);
            const bf16x8 b0 = frg(Bs, wn + l31,      cb);
            const bf16x8 b1 = frg(Bs, wn + 32 + l31, cb);
            acc[0][0] = __builtin_amdgcn_mfma_f32_32x32x16_bf16(a0, b0, acc[0][0], 0, 0, 0);
            acc[0][1] = __builtin_amdgcn_mfma_f32_32x32x16_bf16(a0, b1, acc[0][1], 0, 0, 0);
            acc[1][0] = __builtin_amdgcn_mfma_f32_32x32x16_bf16(a1, b0, acc[1][0], 0, 0, 0);
            acc[1][1] = __builtin_amdgcn_mfma_f32_32x32x16_bf16(a1, b1, acc[1][1], 0, 0, 0);
        }
        __builtin_amdgcn_s_barrier();   // WAR guard: next stage overwrites As/Bs
        asm volatile("" ::: "memory");
    }

    const int flag = *flagp;
    float*          outf = (float*)outv;
    unsigned short* outh = (unsigned short*)outv;
#pragma unroll
    for (int nj = 0; nj < 2; nj++) {
        const int   e    = bn + wn + nj * 32 + l31;
        const float bias = bf2f(bo[e]);
#pragma unroll
        for (int mi = 0; mi < 2; mi++) {
#pragma unroll
            for (int reg = 0; reg < 16; reg++) {
                const int   mrow = bm + wm + mi * 32 + (reg & 3) + 8 * (reg >> 2) + 4 * half;
                const float v = acc[mi][nj][reg] + bias;
                if (flag) outf[(size_t)mrow * DM + e] = v;
                else      outh[(size_t)mrow * DM + e] = f2bf(v);
            }
        }
    }
}

// ---------------------------------------------------------------------------
extern "C" void kernel_launch(void* const* d_in, const int* in_sizes, int n_in,
                              void* d_out, int out_size, void* d_ws, size_t ws_size,
                              hipStream_t stream) {
    // Bind inputs by ELEMENT COUNT (dtype/mask-presence robust)
    const void* x = nullptr;
    const void* Wsrc[4] = {nullptr, nullptr, nullptr, nullptr};
    const void* bsrc[4] = {nullptr, nullptr, nullptr, nullptr};
    int nw = 0, nb = 0;
    for (int i = 0; i < n_in; i++) {
        const int sz = in_sizes[i];
        if (sz == Bz * Sz * DM)            { if (!x) x = d_in[i]; }
        else if (sz == DM * DM)            { if (nw < 4) Wsrc[nw++] = d_in[i]; }
        else if (sz == DM)                 { if (nb < 4) bsrc[nb++] = d_in[i]; }
    }

    char* wsb = (char*)d_ws;
    int*  flagp = (int*)wsb;
    unsigned short* Xc  = (unsigned short*)(wsb + 16);
    const size_t NX = (size_t)Bz * Sz * DM;       // 8,388,608
    const size_t NW = (size_t)DM * DM;            // 1,048,576
    unsigned short* Wc0 = Xc  + NX;
    unsigned short* Wc1 = Wc0 + NW;
    unsigned short* Wc2 = Wc1 + NW;
    unsigned short* Wc3 = Wc2 + NW;
    unsigned short* bc0 = Wc3 + NW;
    unsigned short* bc1 = bc0 + DM;
    unsigned short* bc2 = bc1 + DM;
    unsigned short* bc3 = bc2 + DM;
    unsigned short* Qb  = bc3 + DM;
    const size_t SZ = (size_t)Bz * NH * Sz * DH;  // 8,388,608
    unsigned short* Kb  = Qb  + SZ;
    unsigned short* Vtb = Kb  + SZ;
    unsigned short* AOb = Vtb + SZ;

    detect_dtype<<<1, 64, 0, stream>>>((const unsigned short*)x, flagp);
    convert_inputs<<<dim3(512, 9), 256, 0, stream>>>(
        x, Wsrc[0], Wsrc[1], Wsrc[2], Wsrc[3],
        bsrc[0], bsrc[1], bsrc[2], bsrc[3],
        Xc, Wc0, Wc1, Wc2, Wc3, bc0, bc1, bc2, bc3, flagp);

    gemm_qkv <<<dim3(24, 64), 256, 0, stream>>>(Xc, Wc0, Wc1, Wc2, bc0, bc1, bc2, Qb, Kb, Vtb);
    flash_attn<<<dim3(8, 64), 512, 0, stream>>>(Qb, Kb, Vtb, AOb);
    gemm_out <<<dim3(8, 64), 256, 0, stream>>>(AOb, Wc3, bc3, d_out, flagp);
}